// Round 2
// baseline (481.369 us; speedup 1.0000x reference)
//
#include <hip/hip_runtime.h>
#include <hip/hip_bf16.h>

// Problem constants (GATModule: N=8192, IN=128, OUT=64, H=4) — fp32 inputs/output.
#define NN   8192
#define IND  128
#define OUTD 64
#define NH   4
#define NEG_SLOPE 0.2f
#define BN_EPS 1e-5f

typedef __attribute__((ext_vector_type(8))) short     bf16x8;  // bf16 MFMA frag (k1)
typedef __attribute__((ext_vector_type(8))) _Float16  f16x8;   // f16 MFMA frag (k2)
typedef __attribute__((ext_vector_type(2))) _Float16  h2;      // packed f16 pair
typedef __attribute__((ext_vector_type(4))) float     f32x4;
typedef __attribute__((ext_vector_type(4))) int       i32x4;

union V4 { i32x4 i; f16x8 v; };   // 16B reinterpret between int words and f16x8 frag

static __device__ __forceinline__ short f2bf(float f) {
    union { float f; unsigned u; } v; v.f = f;
    return (short)((v.u + 0x8000u) >> 16);
}
static __device__ __forceinline__ unsigned short f2h(float f) {
    union { _Float16 h; unsigned short s; } u; u.h = (_Float16)f; return u.s;
}

// ---------------- K0: repack W[h][k][o] fp32 -> WB bf16 [h][k/8][o][k%8] (B-frag) ----------
__global__ __launch_bounds__(256) void k0_repackW(const float* __restrict__ W,
                                                  short* __restrict__ WB) {
    int tid = blockIdx.x * 256 + threadIdx.x;      // 0..32767
    int o = tid & 63, i = (tid >> 6) & 127, h = tid >> 13;
    WB[((h * 16 + (i >> 3)) * 64 + o) * 8 + (i & 7)] = f2bf(W[(h * 128 + i) * 64 + o]);
}

// ---------------- K1: h = x@W per head (MFMA); store hF f16 + f16 tables -------------------
// t_Ri = exp(-0.8 ei) fp32; tE1 = f16(exp(ej)); tE2 = f16(exp(0.2 ej)).
// Row-rescaled P via the max identity: exp(leakyrelu(ei+ej))/exp(ei) = max(E1j, Ri*E2j).
__global__ __launch_bounds__(256) void k1_feat(const float* __restrict__ x,
                                               const short* __restrict__ WB,
                                               const float* __restrict__ a_i,
                                               const float* __restrict__ a_j,
                                               unsigned short* __restrict__ hF,
                                               float* __restrict__ t_Ri,
                                               unsigned short* __restrict__ tE1,
                                               unsigned short* __restrict__ tE2) {
    int w = threadIdx.x >> 6;        // head
    int l = threadIdx.x & 63;
    int quad = l >> 4, lx = l & 15;
    int rb = blockIdx.x;             // 16-row block

    f32x4 acc[4] = {};               // 4 o-tiles of 16
#pragma unroll
    for (int ks = 0; ks < 4; ++ks) { // K=128 in 4 steps of 32
        const float* xp = x + (rb * 16 + lx) * IND + ks * 32 + quad * 8;
        f32x4 xa = *(const f32x4*)xp;
        f32x4 xb = *(const f32x4*)(xp + 4);
        bf16x8 af;
#pragma unroll
        for (int j = 0; j < 4; ++j) { af[j] = f2bf(xa[j]); af[4 + j] = f2bf(xb[j]); }
#pragma unroll
        for (int ot = 0; ot < 4; ++ot) {
            bf16x8 bf = *(const bf16x8*)(WB + ((w * 16 + ks * 4 + quad) * 64 + ot * 16 + lx) * 8);
            acc[ot] = __builtin_amdgcn_mfma_f32_16x16x32_bf16(af, bf, acc[ot], 0, 0, 0);
        }
    }
    float aiv[4], ajv[4];
#pragma unroll
    for (int ot = 0; ot < 4; ++ot) {
        aiv[ot] = a_i[w * 64 + ot * 16 + lx];
        ajv[ot] = a_j[w * 64 + ot * 16 + lx];
    }
#pragma unroll
    for (int reg = 0; reg < 4; ++reg) {
        int row = rb * 16 + quad * 4 + reg;       // C-layout: row=quad*4+reg, col=lane&15
        float ei = 0.f, ej = 0.f;
#pragma unroll
        for (int ot = 0; ot < 4; ++ot) {
            float hv = acc[ot][reg];
            ei += hv * aiv[ot];
            ej += hv * ajv[ot];
        }
#pragma unroll
        for (int m = 1; m <= 8; m <<= 1) {        // reduce over the 16 lanes of this row
            ei += __shfl_xor(ei, m, 64);
            ej += __shfl_xor(ej, m, 64);
        }
        if (lx == reg) {
            t_Ri[w * NN + row] = expf(-0.8f * ei);
            tE1[w * NN + row] = f2h(expf(ej));
            tE2[w * NN + row] = f2h(expf(NEG_SLOPE * ej));
        }
#pragma unroll
        for (int ot = 0; ot < 4; ++ot) {          // hF[h][n/8][o][n%8], f16
            int o = ot * 16 + lx;
            hF[((w * 1024 + (row >> 3)) * 64 + o) * 8 + (row & 7)] = f2h(acc[ot][reg]);
        }
    }
}

// ---------------- K2: attention (8 K-splits; f16 pk-math; LDS LUT mult-mask) ---------------
// grid 1024 = 128 rowblocks(64) x 8 K-splits(1024 cols); block 256 = 4 waves, wave w = head.
// vs round-11: (a) 8 K-splits -> 4 blocks/CU (was grid-limited at 2, Occ 20.5%);
// (b) tables+h in f16, P' = pk_mul(pk_max(E1, Ri*E2), lut[maskbyte]) — the per-element
// and+cmp+cndmask mask select, the f32 unpack and the v_perm repack are all gone;
// (c) interleaved bitmask layout: the 4 row-subtile mask bytes for (kt,quad,lx) arrive
// in ONE ds_read_b32. Distance-1 prefetch of tables/hF/mask word kept (measured best).
__global__ __launch_bounds__(256) void k2_attn(const int* __restrict__ adj,
                                               const unsigned short* __restrict__ hF,
                                               const float* __restrict__ t_Ri,
                                               const unsigned short* __restrict__ tE1,
                                               const unsigned short* __restrict__ tE2,
                                               float* __restrict__ num,
                                               float* __restrict__ Lsum) {
    __shared__ unsigned char smask[128 * 68];  // [cg][rl*4+rh]: byte = mask(row rh*16+rl, cg)
    __shared__ unsigned int  lutm[256 * 4];    // mask byte -> 4 f16x2 mult-masks (1.0/0.0)
    int tid = threadIdx.x;
    int w = tid >> 6;                          // head
    int l = tid & 63;
    int quad = l >> 4, lx = l & 15;
    int rb = blockIdx.x & 127, ks = blockIdx.x >> 7;   // consecutive blocks share hF k-slice
    int rowbase = rb * 64;
    int tb = w * NN;
    int k0 = ks * 1024;

    // ---- LUT build: byte b -> 4 words; word jj = [bit(2jj+1)?1.0:0 | bit(2jj)?1.0:0] f16
    {
        unsigned b = (unsigned)tid;
        i32x4 e;
#pragma unroll
        for (int jj = 0; jj < 4; ++jj) {
            unsigned lo = (b >> (2 * jj)) & 1u, hi = (b >> (2 * jj + 1)) & 1u;
            e[jj] = (int)(lo * 0x3C00u + hi * 0x3C000000u);
        }
        *(i32x4*)&lutm[tid * 4] = e;
    }

    // ---- Phase 1: stage adj slice (64 x 1024) -> interleaved LDS bitmask, coalesced ----
    {
        int cg = tid & 127, half = tid >> 7;   // colgroup (8 cols), row-half
        const int* abase = adj + (size_t)rowbase * NN + k0 + cg * 8;
#pragma unroll 2
        for (int rr = 0; rr < 8; ++rr) {
            int rl = half * 8 + rr;
            unsigned mword = 0;
#pragma unroll
            for (int rh = 0; rh < 4; ++rh) {   // byte rh of word = row rh*16+rl
                const int* ap = abase + (size_t)(rh * 16 + rl) * NN;
                i32x4 a0 = *(const i32x4*)ap;
                i32x4 a1 = *(const i32x4*)(ap + 4);
                unsigned m = 0;
#pragma unroll
                for (int j = 0; j < 4; ++j) {
                    m |= (a0[j] ? 1u : 0u) << j;
                    m |= (a1[j] ? 1u : 0u) << (4 + j);
                }
                mword |= m << (8 * rh);
            }
            *(unsigned int*)&smask[cg * 68 + rl * 4] = mword;  // stride 68: conflict-free
        }
    }
    __syncthreads();

    h2 Rh2[4];
#pragma unroll
    for (int r = 0; r < 4; ++r) {              // A row for subtile r: r*16 + lx
        _Float16 rv = (_Float16)t_Ri[tb + rowbase + r * 16 + lx];
        Rh2[r][0] = rv; Rh2[r][1] = rv;
    }

    V4 ones;                                   // B = all ones -> MFMA row sums
#pragma unroll
    for (int jj = 0; jj < 4; ++jj) ones.i[jj] = 0x3C003C00;

    f32x4 acc[4][4] = {};                      // [m-tile][o-tile]
    f32x4 accL[4] = {};                        // row-sum accumulators

    // -------- distance-1 prefetch: f16 table vectors + hF B-frags + mask word --------
    i32x4 p1, p2;
    V4 pbf[4];
    unsigned pm32;
    {
        int kb = k0 + quad * 8;                // kt = 0
        p1 = *(const i32x4*)(tE1 + tb + kb);
        p2 = *(const i32x4*)(tE2 + tb + kb);
#pragma unroll
        for (int ot = 0; ot < 4; ++ot)
            pbf[ot].i = *(const i32x4*)(hF + ((w * 1024 + (kb >> 3)) * 64 + ot * 16 + lx) * 8);
        pm32 = *(const unsigned int*)&smask[quad * 68 + lx * 4];
    }

#pragma unroll 2
    for (int kt = 0; kt < 32; ++kt) {
        // rotate: current <- prefetched (unroll-2 renames these, no movs)
        i32x4 t1 = p1, t2 = p2;
        unsigned m32 = pm32;
        V4 bfrag[4];
#pragma unroll
        for (int ot = 0; ot < 4; ++ot) bfrag[ot] = pbf[ot];

        // issue NEXT iteration's loads first (wrap on last iter — harmless re-read)
        int ktn = (kt + 1) & 31;
        int kbn = k0 + ktn * 32 + quad * 8;
        p1 = *(const i32x4*)(tE1 + tb + kbn);
        p2 = *(const i32x4*)(tE2 + tb + kbn);
#pragma unroll
        for (int ot = 0; ot < 4; ++ot)
            pbf[ot].i = *(const i32x4*)(hF + ((w * 1024 + (kbn >> 3)) * 64 + ot * 16 + lx) * 8);
        pm32 = *(const unsigned int*)&smask[(ktn * 4 + quad) * 68 + lx * 4];

        // build P' (A-frags): p' = lut_mask * max(E1j, Ri*E2j)  — all v_pk_*_f16
        V4 afr[4];
#pragma unroll
        for (int r = 0; r < 4; ++r) {
            V4 mw;
            mw.i = *(const i32x4*)&lutm[((m32 >> (8 * r)) & 0xFFu) * 4];
#pragma unroll
            for (int jj = 0; jj < 4; ++jj) {
                h2 e1 = __builtin_bit_cast(h2, (unsigned)t1[jj]);
                h2 e2 = __builtin_bit_cast(h2, (unsigned)t2[jj]);
                h2 mk = __builtin_bit_cast(h2, (unsigned)mw.i[jj]);
                h2 p  = __builtin_elementwise_max(e1, Rh2[r] * e2) * mk;
                afr[r].i[jj] = (int)__builtin_bit_cast(unsigned, p);
            }
        }
#pragma unroll
        for (int r = 0; r < 4; ++r)            // row sums on the MFMA pipe (B = ones)
            accL[r] = __builtin_amdgcn_mfma_f32_16x16x32_f16(afr[r].v, ones.v, accL[r], 0, 0, 0);
#pragma unroll
        for (int r = 0; r < 4; ++r)
#pragma unroll
            for (int ot = 0; ot < 4; ++ot)
                acc[r][ot] = __builtin_amdgcn_mfma_f32_16x16x32_f16(afr[r].v, bfrag[ot].v, acc[r][ot], 0, 0, 0);
    }

    // softmax denominators: accL[r][reg] holds rowsum(row=quad*4+reg) in every col lane
#pragma unroll
    for (int r = 0; r < 4; ++r)
        if (lx == 0)
#pragma unroll
            for (int reg = 0; reg < 4; ++reg)
                atomicAdd(&Lsum[w * NN + rowbase + r * 16 + quad * 4 + reg], accL[r][reg]);
    // numerator: atomic combine across the 8 K-splits
#pragma unroll
    for (int r = 0; r < 4; ++r)
#pragma unroll
        for (int ot = 0; ot < 4; ++ot)
#pragma unroll
            for (int reg = 0; reg < 4; ++reg) {
                int row = rowbase + r * 16 + quad * 4 + reg;    // C/D: row=quad*4+reg
                atomicAdd(&num[row * 256 + w * 64 + ot * 16 + lx], acc[r][ot][reg]);
            }
}

// ---------------- K3: BN partial stats only (no val write; k5 re-divides) ------------------
// grid 1024 blocks x 8 rows; thread t = column c (h*64+o)
__global__ __launch_bounds__(256) void k3_stats(const float* __restrict__ num,
                                                const float* __restrict__ Lsum,
                                                float* __restrict__ stats) {
    int c = threadIdx.x;
    int h = c >> 6;
    float s = 0.f, s2 = 0.f;
#pragma unroll
    for (int rr = 0; rr < 8; ++rr) {
        int row = blockIdx.x * 8 + rr;
        float val = num[row * 256 + c] / Lsum[h * NN + row];
        s += val; s2 += val * val;
    }
    atomicAdd(&stats[c], s);
    atomicAdd(&stats[c + 256], s2);
}

// ---------------- K5: BN finalize (LDS) + divide + apply + ReLU -> fp32 out ----------------
__global__ __launch_bounds__(256) void k5_apply(const float* __restrict__ num,
                                                const float* __restrict__ Lsum,
                                                const float* __restrict__ stats,
                                                const float* __restrict__ gamma,
                                                const float* __restrict__ beta,
                                                float* __restrict__ out) {
    __shared__ float sbnp[512];
    int c = threadIdx.x;
    float mean = stats[c] * (1.0f / NN);
    float var  = stats[c + 256] * (1.0f / NN) - mean * mean;
    float sc = gamma[c] * rsqrtf(var + BN_EPS);
    sbnp[c] = sc;
    sbnp[c + 256] = beta[c] - mean * sc;
    __syncthreads();

    int g = blockIdx.x * 256 + threadIdx.x;        // float4 index, 524288 total
    f32x4 v = *(const f32x4*)(num + (size_t)g * 4);
    int cb = (g * 4) & 255;
    int row = g >> 6;
    float rL = 1.0f / Lsum[(cb >> 6) * NN + row];
    f32x4 r;
#pragma unroll
    for (int j = 0; j < 4; ++j)
        r[j] = fmaxf((v[j] * rL) * sbnp[cb + j] + sbnp[256 + cb + j], 0.0f);
    *(f32x4*)(out + (size_t)g * 4) = r;
}

extern "C" void kernel_launch(void* const* d_in, const int* in_sizes, int n_in,
                              void* d_out, int out_size, void* d_ws, size_t ws_size,
                              hipStream_t stream) {
    (void)in_sizes; (void)n_in; (void)out_size; (void)ws_size;
    const float* x     = (const float*)d_in[0];
    const int*   adj   = (const int*)d_in[1];
    const float* W     = (const float*)d_in[2];
    const float* a_i   = (const float*)d_in[3];
    const float* a_j   = (const float*)d_in[4];
    const float* gamma = (const float*)d_in[5];
    const float* beta  = (const float*)d_in[6];
    float* out = (float*)d_out;

    char* ws = (char*)d_ws;
    // workspace layout (~13 MB). num|Lsum|stats contiguous -> single memset.
    short*          WB    = (short*)(ws + 0);             //   64 KB (bf16 W, B-frag layout)
    unsigned short* hF    = (unsigned short*)(ws + 65536);        //  4 MB (f16 h, B-frag layout)
    float*          t_Ri  = (float*)(ws + 4259840);       //  128 KB
    unsigned short* tE1   = (unsigned short*)(ws + 4390912);      //  64 KB f16 exp(ej)
    unsigned short* tE2   = (unsigned short*)(ws + 4456448);      //  64 KB f16 exp(0.2 ej)
    float*          num   = (float*)(ws + 4521984);       //    8 MB (numerator, atomic-combined)
    float*          Lsum  = (float*)(ws + 12910592);      //  128 KB
    float*          stats = (float*)(ws + 13041664);      //    2 KB (atomic accum)

    (void)hipMemsetAsync(num, 0, 8388608 + 131072 + 2048, stream);  // num + Lsum + stats

    k0_repackW<<<dim3(128),  dim3(256), 0, stream>>>(W, WB);
    k1_feat   <<<dim3(512),  dim3(256), 0, stream>>>(x, WB, a_i, a_j, hF, t_Ri, tE1, tE2);
    k2_attn   <<<dim3(1024), dim3(256), 0, stream>>>(adj, hF, t_Ri, tE1, tE2, num, Lsum);
    k3_stats  <<<dim3(1024), dim3(256), 0, stream>>>(num, Lsum, stats);
    k5_apply  <<<dim3(2048), dim3(256), 0, stream>>>(num, Lsum, stats, gamma, beta, out);
}